// Round 14
// baseline (403.174 us; speedup 1.0000x reference)
//
#include <hip/hip_runtime.h>
#include <math.h>

// approxmatch EMD (Fan et al.) — b=8, n=m=2048, f32.
// R14 = R13 + Morton sort + per-chunk bbox underflow-skip.
//  - k_sort: per batch/side, 21-bit Morton key bitonic sort (deterministic,
//    key = morton<<11|idx), writes sorted (x,y,z,|p|^2) + 32 chunk bboxes.
//  - Fat kernels: wave-uniform skip of a 64-j chunk when bbox d2min implies
//    exp2 underflows to exactly 0 for every pair (cut = 152/|kp|; B uses
//    183/|kk| to cover folded log2 f <= 31). Skip templated: only levels
//    with cut < 3 pay the test. Exact: reference f32 exp also gives 0 there.
// 22 dispatches: sort | A0 | 9 x { B_t ; CA_t } | B9 | C9.
//   A: f_i = multiL/(1e-9 + multiR*sum_j e(kk))          [level 0]
//   B: s_j = sum_i f_i e(kk); colsum=R s; rr=min(R/(1e-9+colsum),1);
//      c=R rr; R' = max(R-colsum rr,0)   [f folded: exp2(kk d2 + log2 f)]
//   C: t_i=sum_j c e; u_i=sum_j c e sqrt(d2);
//      remL'=max(remL-f t,0); cost+=f u
// CA_t fuses C_t with A_{t+1} (level_t = 4*level_{t+1} exact for t<8):
// e1=exp2(kk_{t+1} d2) serves C (e1^4) and A (e1).
// Folded exponent: kk*d2 = kk|p|^2 + kk|q|^2 - 2kk(p.q);
// sqrt(d2)=sqrt(|kk d2|)/sqrt(|kk|) hoisted. Rows packed in v2 pairs.

#define NPTS 2048
#define BLOCK 256
#define RPB 16               // rows per block -> 128 blocks/batch, grid 1024
#define L2E 1.4426950408889634f

typedef float v2 __attribute__((ext_vector_type(2)));

__device__ __forceinline__ float fexp2(float x) { return __builtin_amdgcn_exp2f(x); }
__device__ __forceinline__ float fsqrt(float x) { return __builtin_amdgcn_sqrtf(x); }
__device__ __forceinline__ float flog2(float x) { return __builtin_amdgcn_logf(x); }
__device__ __forceinline__ v2 fma2(v2 a, v2 b, v2 c) { return __builtin_elementwise_fma(a, b, c); }
__device__ __forceinline__ v2 sp(float a) { v2 r; r.x = a; r.y = a; return r; }
__device__ __forceinline__ float xreduce(float v) {
#pragma unroll
    for (int off = 1; off < 64; off <<= 1) v += __shfl_xor(v, off, 64);
    return v;
}

struct RowPair { v2 pa, px, py, pz; };
__device__ __forceinline__ RowPair mk_pair(float4 a, float4 b, float kp) {
    RowPair r;
    r.pa = v2{kp * a.w, kp * b.w};          // .w holds |p|^2 (from k_sort)
    r.px = v2{-2.f*kp*a.x, -2.f*kp*b.x};
    r.py = v2{-2.f*kp*a.y, -2.f*kp*b.y};
    r.pz = v2{-2.f*kp*a.z, -2.f*kp*b.z};
    return r;
}
__device__ __forceinline__ v2 term(const RowPair& r, float qx, float qy, float qz, v2 qb2) {
    return fma2(r.px, sp(qx), fma2(r.py, sp(qy), fma2(r.pz, sp(qz), r.pa + qb2)));
}

// bbox over 16 consecutive sorted points (block's rows/cols); uniform result.
__device__ __forceinline__ void bbox16(const float4* __restrict__ p, int start, int lane,
                                       float& lx, float& ly, float& lz,
                                       float& hx, float& hy, float& hz) {
    float4 q = p[start + (lane & 15)];
    lx = q.x; hx = q.x; ly = q.y; hy = q.y; lz = q.z; hz = q.z;
#pragma unroll
    for (int off = 1; off < 16; off <<= 1) {
        lx = fminf(lx, __shfl_xor(lx, off, 64));
        hx = fmaxf(hx, __shfl_xor(hx, off, 64));
        ly = fminf(ly, __shfl_xor(ly, off, 64));
        hy = fmaxf(hy, __shfl_xor(hy, off, 64));
        lz = fminf(lz, __shfl_xor(lz, off, 64));
        hz = fmaxf(hz, __shfl_xor(hz, off, 64));
    }
}

__device__ __forceinline__ unsigned spread3(unsigned v) {
    v &= 0x3FFu;
    v = (v | (v << 16)) & 0x030000FFu;
    v = (v | (v << 8))  & 0x0300F00Fu;
    v = (v | (v << 4))  & 0x030C30C3u;
    v = (v | (v << 2))  & 0x09249249u;
    return v;
}

// Per (batch, side): Morton-sort points (deterministic bitonic on
// key = morton21<<11 | idx), write sorted (x,y,z,|p|^2) + 32 chunk bboxes.
__global__ __launch_bounds__(256) void k_sort(
    const float* __restrict__ xyz1, const float* __restrict__ xyz2,
    float4* __restrict__ p1w, float4* __restrict__ p2w,
    float4* __restrict__ bb1, float4* __restrict__ bb2)
{
    __shared__ float sx[NPTS], sy[NPTS], sz[NPTS];
    __shared__ unsigned skey[NPTS];
    const int batch = blockIdx.x >> 1;
    const int side  = blockIdx.x & 1;
    const float* src = (side ? xyz2 : xyz1) + (size_t)batch * NPTS * 3;
    float4* dst = (side ? p2w : p1w) + ((size_t)batch << 11);
    float4* bb  = (side ? bb2 : bb1) + batch * 64;
    const int tid = threadIdx.x;
    for (int i = tid; i < NPTS; i += 256) {
        float x = src[3*i], y = src[3*i+1], z = src[3*i+2];
        sx[i] = x; sy[i] = y; sz[i] = z;
        int cx = (int)(x * 128.f); cx = cx < 0 ? 0 : (cx > 127 ? 127 : cx);
        int cy = (int)(y * 128.f); cy = cy < 0 ? 0 : (cy > 127 ? 127 : cy);
        int cz = (int)(z * 128.f); cz = cz < 0 ? 0 : (cz > 127 ? 127 : cz);
        unsigned m = (spread3((unsigned)cx) << 2) | (spread3((unsigned)cy) << 1)
                   | spread3((unsigned)cz);
        skey[i] = (m << 11) | (unsigned)i;
    }
    for (unsigned k = 2; k <= NPTS; k <<= 1) {
        for (unsigned j = k >> 1; j > 0; j >>= 1) {
            __syncthreads();
            for (int i = tid; i < NPTS; i += 256) {
                int l = i ^ (int)j;
                if (l > i) {
                    unsigned a = skey[i], b = skey[l];
                    bool up = ((i & (int)k) == 0);
                    if ((a > b) == up) { skey[i] = b; skey[l] = a; }
                }
            }
        }
    }
    __syncthreads();
    for (int i = tid; i < NPTS; i += 256) {
        unsigned idx = skey[i] & 2047u;
        float x = sx[idx], y = sy[idx], z = sz[idx];
        dst[i] = make_float4(x, y, z, x*x + y*y + z*z);
    }
    const int wave = tid >> 6, lane = tid & 63;
    for (int c = wave; c < 32; c += 4) {
        unsigned idx = skey[c * 64 + lane] & 2047u;
        float x = sx[idx], y = sy[idx], z = sz[idx];
        float lx=x,hx=x,ly=y,hy=y,lz=z,hz=z;
#pragma unroll
        for (int off = 1; off < 64; off <<= 1) {
            lx = fminf(lx, __shfl_xor(lx, off, 64));
            hx = fmaxf(hx, __shfl_xor(hx, off, 64));
            ly = fminf(ly, __shfl_xor(ly, off, 64));
            hy = fmaxf(hy, __shfl_xor(hy, off, 64));
            lz = fminf(lz, __shfl_xor(lz, off, 64));
            hz = fmaxf(hz, __shfl_xor(hz, off, 64));
        }
        if (lane == 0) {
            bb[2*c]   = make_float4(lx, ly, lz, 0.f);
            bb[2*c+1] = make_float4(hx, hy, hz, 0.f);
        }
    }
}

// Level-0 rows pass (skip always on: cut = 152/|kk0| tiny).
__global__ __launch_bounds__(BLOCK) void k_A(
    const float4* __restrict__ p1w, const float4* __restrict__ p2w,
    const float4* __restrict__ bb2, float* __restrict__ f_g,
    float kk, float cutd2, float multiL, float multiR)
{
    __shared__ float4 sQ[NPTS];
    __shared__ float4 sBB[64];
    const int row0 = blockIdx.x * RPB;
    const int batch = row0 >> 11;
    const float4* P2 = p2w + ((size_t)batch << 11);
    for (int j = threadIdx.x; j < NPTS; j += BLOCK) {
        float4 q = P2[j]; q.w *= kk; sQ[j] = q;
    }
    if (threadIdx.x < 64) sBB[threadIdx.x] = bb2[batch * 64 + threadIdx.x];
    __syncthreads();
    const int lane = threadIdx.x & 63;
    const int wave = threadIdx.x >> 6;
    const int r0 = row0 + wave * 4;
    RowPair rA = mk_pair(p1w[r0],   p1w[r0+1], kk);
    RowPair rB = mk_pair(p1w[r0+2], p1w[r0+3], kk);
    float lx, ly, lz, hx, hy, hz;
    bbox16(p1w, row0, lane, lx, ly, lz, hx, hy, hz);
    v2 aSA = sp(0.f), aSB = sp(0.f);
#pragma unroll 1
    for (int it = 0; it < NPTS / 64; ++it) {
        float4 blo = sBB[2*it], bhi = sBB[2*it+1];
        float gx = fmaxf(fmaxf(blo.x - hx, lx - bhi.x), 0.f);
        float gy = fmaxf(fmaxf(blo.y - hy, ly - bhi.y), 0.f);
        float gz = fmaxf(fmaxf(blo.z - hz, lz - bhi.z), 0.f);
        if (fmaf(gx, gx, fmaf(gy, gy, gz * gz)) > cutd2) continue;
        float4 q = sQ[it * 64 + lane];
        v2 qb2 = sp(q.w);
        v2 tA = term(rA, q.x, q.y, q.z, qb2);
        v2 tB = term(rB, q.x, q.y, q.z, qb2);
        aSA += v2{fexp2(tA.x), fexp2(tA.y)};
        aSB += v2{fexp2(tB.x), fexp2(tB.y)};
    }
    float sv[4] = {xreduce(aSA.x), xreduce(aSA.y), xreduce(aSB.x), xreduce(aSB.y)};
    if (lane == 0) {
#pragma unroll
        for (int r = 0; r < 4; ++r)
            f_g[r0 + r] = multiL / (1e-9f + multiR * sv[r]);
    }
}

// Cols pass, t<=8. LDS 33KB. f folded into exponent via log2.
template <bool FIRST, bool SKIP>
__global__ __launch_bounds__(BLOCK) void k_B(
    const float4* __restrict__ p1w, const float4* __restrict__ p2w,
    const float4* __restrict__ bb1, const float* __restrict__ f_g,
    float* __restrict__ remR, float* __restrict__ c_g,
    float kk, float cutd2, float multiR)
{
    __shared__ float4 sQ[NPTS];              // rows: x,y,z, kk*|p|^2 + log2 f
    __shared__ float4 sBB[64];
    const int col0 = blockIdx.x * RPB;
    const int batch = col0 >> 11;
    const float4* P1 = p1w + ((size_t)batch << 11);
    const float* F = f_g + ((size_t)batch << 11);
    for (int i = threadIdx.x; i < NPTS; i += BLOCK) {
        float4 q = P1[i];
        q.w = kk * q.w + flog2(F[i]);
        sQ[i] = q;
    }
    if (threadIdx.x < 64) sBB[threadIdx.x] = bb1[batch * 64 + threadIdx.x];
    __syncthreads();
    const int lane = threadIdx.x & 63;
    const int wave = threadIdx.x >> 6;
    const int c0 = col0 + wave * 4;
    RowPair rA = mk_pair(p2w[c0],   p2w[c0+1], kk);
    RowPair rB = mk_pair(p2w[c0+2], p2w[c0+3], kk);
    float lx, ly, lz, hx, hy, hz;
    bbox16(p2w, col0, lane, lx, ly, lz, hx, hy, hz);
    v2 aSA = sp(0.f), aSB = sp(0.f);
#pragma unroll 1
    for (int it = 0; it < NPTS / 64; ++it) {
        if (SKIP) {
            float4 blo = sBB[2*it], bhi = sBB[2*it+1];
            float gx = fmaxf(fmaxf(blo.x - hx, lx - bhi.x), 0.f);
            float gy = fmaxf(fmaxf(blo.y - hy, ly - bhi.y), 0.f);
            float gz = fmaxf(fmaxf(blo.z - hz, lz - bhi.z), 0.f);
            if (fmaf(gx, gx, fmaf(gy, gy, gz * gz)) > cutd2) continue;
        }
        float4 p = sQ[it * 64 + lane];
        v2 qb2 = sp(p.w);
        v2 tA = term(rA, p.x, p.y, p.z, qb2);
        v2 tB = term(rB, p.x, p.y, p.z, qb2);
        aSA += v2{fexp2(tA.x), fexp2(tA.y)};
        aSB += v2{fexp2(tB.x), fexp2(tB.y)};
    }
    float sv[4] = {xreduce(aSA.x), xreduce(aSA.y), xreduce(aSB.x), xreduce(aSB.y)};
    if (lane == 0) {
#pragma unroll
        for (int r = 0; r < 4; ++r) {
            int gj = c0 + r;
            float R = FIRST ? multiR : remR[gj];
            float colsum = R * sv[r];
            float rr = fminf(R / (1e-9f + colsum), 1.0f);
            c_g[gj] = R * rr;
            remR[gj] = fmaxf(R - colsum * rr, 0.f);
        }
    }
}

// B_9 (kk=0): s_j = sum_i f_i (const per batch); zeroes out[batch].
__global__ __launch_bounds__(BLOCK) void k_B9(
    const float* __restrict__ f_g, const float* __restrict__ remR,
    float* __restrict__ c_g, float* __restrict__ out)
{
    __shared__ float wsum[BLOCK / 64];
    const int batch = blockIdx.x;
    const float* F = f_g + ((size_t)batch << 11);
    float s = 0.f;
    for (int i = threadIdx.x; i < NPTS; i += BLOCK) s += F[i];
    s = xreduce(s);
    int wave = threadIdx.x >> 6, lane = threadIdx.x & 63;
    if (lane == 0) wsum[wave] = s;
    __syncthreads();
    float Ftot = (wsum[0] + wsum[1]) + (wsum[2] + wsum[3]);
    if (threadIdx.x == 0) out[batch] = 0.f;
    for (int j = threadIdx.x; j < NPTS; j += BLOCK) {
        int gj = (batch << 11) + j;
        float R = remR[gj];
        float colsum = R * Ftot;
        float rr = fminf(R / (1e-9f + colsum), 1.0f);
        c_g[gj] = R * rr;
    }
}

// Rows pass: C_t fused with A_{t+1}, t=0..8. LDS 49KB.
// MODE 1: t<8: kp=kk_{t+1}; C-weight=e1^4; aA += rw*e1. SKIP allowed.
// MODE 2: t=8: kp=kk_8; C-weight=e1; aA = sum rw (hoisted). No skip.
template <int MODE, bool FIRSTC, bool SKIP>
__global__ __launch_bounds__(BLOCK) void k_CA(
    const float4* __restrict__ p1w, const float4* __restrict__ p2w,
    const float4* __restrict__ bb2, float* __restrict__ f_g,
    const float* __restrict__ c_g, const float* __restrict__ remR,
    float* __restrict__ remL, float* __restrict__ costrow,
    float kp, float rsqkp, float cutd2, float multiL)
{
    __shared__ float4 sQ[NPTS];              // x,y,z, kp*|q|^2
    __shared__ float2 sCR[NPTS];             // c, r
    __shared__ float4 sBB[64];
    const int row0 = blockIdx.x * RPB;
    const int batch = row0 >> 11;
    const float4* P2 = p2w + ((size_t)batch << 11);
    const float* C = c_g + ((size_t)batch << 11);
    const float* R = remR + ((size_t)batch << 11);
    for (int j = threadIdx.x; j < NPTS; j += BLOCK) {
        float4 q = P2[j];
        q.w *= kp;
        sQ[j] = q;
        sCR[j] = make_float2(C[j], R[j]);
    }
    if (threadIdx.x < 64) sBB[threadIdx.x] = bb2[batch * 64 + threadIdx.x];
    __syncthreads();
    const int lane = threadIdx.x & 63;
    const int wave = threadIdx.x >> 6;
    const int r0 = row0 + wave * 4;

    RowPair rA = mk_pair(p1w[r0],   p1w[r0+1], kp);
    RowPair rB = mk_pair(p1w[r0+2], p1w[r0+3], kp);
    v2 fiA = v2{f_g[r0], f_g[r0+1]}, fiB = v2{f_g[r0+2], f_g[r0+3]};
    float lx, ly, lz, hx, hy, hz;
    bbox16(p1w, row0, lane, lx, ly, lz, hx, hy, hz);
    v2 aTA = sp(0.f), aTB = sp(0.f), aUA = sp(0.f), aUB = sp(0.f);
    v2 aAA = sp(0.f), aAB = sp(0.f);
    float aAs = 0.f;
#pragma unroll 1
    for (int it = 0; it < NPTS / 64; ++it) {
        if (SKIP) {
            float4 blo = sBB[2*it], bhi = sBB[2*it+1];
            float gx = fmaxf(fmaxf(blo.x - hx, lx - bhi.x), 0.f);
            float gy = fmaxf(fmaxf(blo.y - hy, ly - bhi.y), 0.f);
            float gz = fmaxf(fmaxf(blo.z - hz, lz - bhi.z), 0.f);
            if (fmaf(gx, gx, fmaf(gy, gy, gz * gz)) > cutd2) continue;
        }
        float4 q = sQ[it * 64 + lane];
        float2 crj = sCR[it * 64 + lane];
        v2 qb2 = sp(q.w);
        float cw = crj.x, rw = crj.y;
        if (MODE == 2) aAs += rw;
        v2 tA = term(rA, q.x, q.y, q.z, qb2);
        v2 tB = term(rB, q.x, q.y, q.z, qb2);
        v2 eA = v2{fexp2(tA.x), fexp2(tA.y)};
        v2 eB = v2{fexp2(tB.x), fexp2(tB.y)};
        v2 eCA, eCB;
        if (MODE == 1) {
            v2 e2A = eA * eA, e2B = eB * eB;
            eCA = sp(cw) * (e2A * e2A); eCB = sp(cw) * (e2B * e2B);
        } else {
            eCA = sp(cw) * eA; eCB = sp(cw) * eB;
        }
        aTA += eCA; aTB += eCB;
        v2 stA = v2{fsqrt(fabsf(tA.x)), fsqrt(fabsf(tA.y))};
        v2 stB = v2{fsqrt(fabsf(tB.x)), fsqrt(fabsf(tB.y))};
        aUA = fma2(eCA, stA, aUA); aUB = fma2(eCB, stB, aUB);
        if (MODE == 1) { aAA = fma2(sp(rw), eA, aAA); aAB = fma2(sp(rw), eB, aAB); }
    }
    float aas = (MODE == 2) ? xreduce(aAs) : 0.f;
    float tt[4] = {xreduce(aTA.x), xreduce(aTA.y), xreduce(aTB.x), xreduce(aTB.y)};
    float uu[4] = {xreduce(aUA.x), xreduce(aUA.y), xreduce(aUB.x), xreduce(aUB.y)};
    float aav[4];
    if (MODE == 1) {
        aav[0] = xreduce(aAA.x); aav[1] = xreduce(aAA.y);
        aav[2] = xreduce(aAB.x); aav[3] = xreduce(aAB.y);
    } else {
        aav[0] = aav[1] = aav[2] = aav[3] = aas;
    }
    float fiv[4] = {fiA.x, fiA.y, fiB.x, fiB.y};
    if (lane == 0) {
#pragma unroll
        for (int r = 0; r < 4; ++r) {
            int gi = r0 + r;
            float rl0 = FIRSTC ? multiL : remL[gi];
            float rl = fmaxf(rl0 - fiv[r] * tt[r], 0.f);
            costrow[gi] = (FIRSTC ? 0.f : costrow[gi]) + fiv[r] * uu[r] * rsqkp;
            remL[gi] = rl;
            f_g[gi] = rl / (1e-9f + aav[r]);
        }
    }
}

// Final level (kk=0): e==1 -> u_i = sum_j c_j sqrt(d2);
// out[batch] += costrow_i + f_i*u_i  (k_cost fused; no skip possible).
__global__ __launch_bounds__(BLOCK) void k_C9(
    const float4* __restrict__ p1w, const float4* __restrict__ p2w,
    const float* __restrict__ f_g, const float* __restrict__ c_g,
    const float* __restrict__ costrow, float* __restrict__ out)
{
    __shared__ float4 sQ[NPTS];
    __shared__ float sC[NPTS];
    __shared__ float wsum[BLOCK / 64];
    const int row0 = blockIdx.x * RPB;
    const int batch = row0 >> 11;
    const float4* P2 = p2w + ((size_t)batch << 11);
    const float* C = c_g + ((size_t)batch << 11);
    for (int j = threadIdx.x; j < NPTS; j += BLOCK) {
        sQ[j] = P2[j];
        sC[j] = C[j];
    }
    __syncthreads();
    const int lane = threadIdx.x & 63;
    const int wave = threadIdx.x >> 6;
    const int r0 = row0 + wave * 4;
    float px[4], py[4], pz[4], aU[4];
#pragma unroll
    for (int r = 0; r < 4; ++r) {
        float4 q = p1w[r0 + r];
        px[r] = q.x; py[r] = q.y; pz[r] = q.z; aU[r] = 0.f;
    }
#pragma unroll 4
    for (int j = lane; j < NPTS; j += 64) {
        float4 q = sQ[j];
        float cw = sC[j];
#pragma unroll
        for (int r = 0; r < 4; ++r) {
            float dx = px[r]-q.x, dy = py[r]-q.y, dz = pz[r]-q.z;
            float d2 = fmaf(dx, dx, fmaf(dy, dy, dz * dz));
            aU[r] = fmaf(cw, fsqrt(d2), aU[r]);
        }
    }
    float psum = 0.f;
#pragma unroll
    for (int r = 0; r < 4; ++r) {
        float uu = xreduce(aU[r]);
        if (lane == 0) psum += costrow[r0 + r] + f_g[r0 + r] * uu;
    }
    if (lane == 0) wsum[wave] = psum;
    __syncthreads();
    if (threadIdx.x == 0)
        atomicAdd(&out[batch], (wsum[0] + wsum[1]) + (wsum[2] + wsum[3]));
}

extern "C" void kernel_launch(void* const* d_in, const int* in_sizes, int n_in,
                              void* d_out, int out_size, void* d_ws, size_t ws_size,
                              hipStream_t stream) {
    const float* xyz1 = (const float*)d_in[0];
    const float* xyz2 = (const float*)d_in[1];
    float* out = (float*)d_out;
    const int b = out_size;                 // 8
    const int n = in_sizes[0] / (3 * b);    // 2048
    const int m = in_sizes[1] / (3 * b);    // 2048
    const int bn = b * n, bm = b * m;

    float4* p1w = (float4*)d_ws;            // bn
    float4* p2w = p1w + bn;                 // bm
    float* remL    = (float*)(p2w + bm);    // bn
    float* remR    = remL + bn;             // bm
    float* f       = remR + bm;             // bn
    float* c       = f + bn;                // bm
    float* costrow = c + bm;                // bn
    float4* bb1    = (float4*)(costrow + bn); // b*64
    float4* bb2    = bb1 + (size_t)b * 64;    // b*64

    const float multiL = (float)((m / n > 1) ? (m / n) : 1);
    const float multiR = (float)((n / m > 1) ? (n / m) : 1);

    dim3 g(bn / RPB), blk(BLOCK);
    k_sort<<<dim3(2 * b), blk, 0, stream>>>(xyz1, xyz2, p1w, p2w, bb1, bb2);

    const float absk0 = 16384.f * L2E;
    k_A<<<g, blk, 0, stream>>>(p1w, p2w, bb2, f, -absk0, 152.f / absk0,
                               multiL, multiR);

    for (int t = 0; t < 9; ++t) {
        const float abskk = exp2f(2.f * (float)(7 - t)) * L2E;
        const float kk = -abskk;
        const float cutB = 183.f / abskk;
        if (t == 0)
            k_B<true, true><<<g, blk, 0, stream>>>(p1w, p2w, bb1, f, remR, c,
                                                   kk, cutB, multiR);
        else if (cutB < 3.0f)
            k_B<false, true><<<g, blk, 0, stream>>>(p1w, p2w, bb1, f, remR, c,
                                                    kk, cutB, multiR);
        else
            k_B<false, false><<<g, blk, 0, stream>>>(p1w, p2w, bb1, f, remR, c,
                                                     kk, cutB, multiR);

        if (t < 8) {
            const float kp = kk * 0.25f;                 // = kk_{t+1}
            const float cutCA = 152.f / (abskk * 0.25f);
            const float rsq = 1.f / sqrtf(-kp);
            if (t == 0)
                k_CA<1, true, true><<<g, blk, 0, stream>>>(p1w, p2w, bb2, f, c,
                    remR, remL, costrow, kp, rsq, cutCA, multiL);
            else if (cutCA < 3.0f)
                k_CA<1, false, true><<<g, blk, 0, stream>>>(p1w, p2w, bb2, f, c,
                    remR, remL, costrow, kp, rsq, cutCA, multiL);
            else
                k_CA<1, false, false><<<g, blk, 0, stream>>>(p1w, p2w, bb2, f, c,
                    remR, remL, costrow, kp, rsq, cutCA, multiL);
        } else {
            const float kp = -0.25f * L2E;               // kk_8
            const float rsq = 1.f / sqrtf(0.25f * L2E);
            k_CA<2, false, false><<<g, blk, 0, stream>>>(p1w, p2w, bb2, f, c,
                remR, remL, costrow, kp, rsq, 1e30f, multiL);
        }
    }
    // t = 9: trivial B (e==1) then fused cost pass.
    k_B9<<<dim3(b), blk, 0, stream>>>(f, remR, c, out);
    k_C9<<<g, blk, 0, stream>>>(p1w, p2w, f, c, costrow, out);
}

// Round 15
// 302.218 us; speedup vs baseline: 1.3341x; 1.3341x over previous
//
#include <hip/hip_runtime.h>
#include <math.h>

// approxmatch EMD (Fan et al.) — b=8, n=m=2048, f32.
// R15 = R13 fat-pass structure (unroll 4/8 loops intact) + Morton-sort-based
// chunk skip, re-engineered after R14's two implementation failures:
//  - k_sort: 1024 thr, 2 pairs/thread, BATCHED pair loads (no serial LDS
//    round-trips) -> ~12us expected.
//  - skip: block-uniform 32-bit survivor mask built once by wave 0
//    (bbox-gap test per chunk, __ballot); main loop pops 2 chunks/iter via
//    ctz -> body ILP ~2. Non-skip instantiations = R13 loops exactly.
//  - skip only where cut < 1: A0, B_0..3, CA_0..2. Skipped chunks contribute
//    exact +0.0f (exp2 underflow, reference does the same) -> absmax 0.
// 22 dispatches: sort | A0 | 9 x { B_t ; CA_t } | B9 | C9.

#define NPTS 2048
#define BLOCK 256
#define RPB 16               // rows per block -> 128 blocks/batch, grid 1024
#define SORT_T 1024
#define L2E 1.4426950408889634f

typedef float v2 __attribute__((ext_vector_type(2)));

__device__ __forceinline__ float fexp2(float x) { return __builtin_amdgcn_exp2f(x); }
__device__ __forceinline__ float fsqrt(float x) { return __builtin_amdgcn_sqrtf(x); }
__device__ __forceinline__ float flog2(float x) { return __builtin_amdgcn_logf(x); }
__device__ __forceinline__ v2 fma2(v2 a, v2 b, v2 c) { return __builtin_elementwise_fma(a, b, c); }
__device__ __forceinline__ v2 sp(float a) { v2 r; r.x = a; r.y = a; return r; }
__device__ __forceinline__ float xreduce(float v) {
#pragma unroll
    for (int off = 1; off < 64; off <<= 1) v += __shfl_xor(v, off, 64);
    return v;
}

struct RowPair { v2 pa, px, py, pz; };
__device__ __forceinline__ RowPair mk_pair(float4 a, float4 b, float kp) {
    RowPair r;
    r.pa = v2{kp * a.w, kp * b.w};          // .w = |p|^2 (from k_sort)
    r.px = v2{-2.f*kp*a.x, -2.f*kp*b.x};
    r.py = v2{-2.f*kp*a.y, -2.f*kp*b.y};
    r.pz = v2{-2.f*kp*a.z, -2.f*kp*b.z};
    return r;
}
__device__ __forceinline__ v2 term(const RowPair& r, float qx, float qy, float qz, v2 qb2) {
    return fma2(r.px, sp(qx), fma2(r.py, sp(qy), fma2(r.pz, sp(qz), r.pa + qb2)));
}

// bbox over the block's 16 own (sorted) points; valid in every lane of the wave.
__device__ __forceinline__ void bbox16(const float4* __restrict__ p, int start, int lane,
                                       float& lx, float& ly, float& lz,
                                       float& hx, float& hy, float& hz) {
    float4 q = p[start + (lane & 15)];
    lx = q.x; hx = q.x; ly = q.y; hy = q.y; lz = q.z; hz = q.z;
#pragma unroll
    for (int off = 1; off < 16; off <<= 1) {
        lx = fminf(lx, __shfl_xor(lx, off, 64));
        hx = fmaxf(hx, __shfl_xor(hx, off, 64));
        ly = fminf(ly, __shfl_xor(ly, off, 64));
        hy = fmaxf(hy, __shfl_xor(hy, off, 64));
        lz = fminf(lz, __shfl_xor(lz, off, 64));
        hz = fmaxf(hz, __shfl_xor(hz, off, 64));
    }
}

// wave 0 builds the 32-bit survivor mask (chunk c survives if bbox gap^2 <= cut).
// Caller must have staged sBB and issued a barrier before calling.
__device__ __forceinline__ unsigned build_mask(
    const float4* __restrict__ pts, int start, int lane, int wave,
    const float4* __restrict__ sBB, float cutd2, unsigned* sMask)
{
    if (wave == 0) {
        float lx, ly, lz, hx, hy, hz;
        bbox16(pts, start, lane, lx, ly, lz, hx, hy, hz);
        bool pred = false;
        if (lane < 32) {
            float4 blo = sBB[2*lane], bhi = sBB[2*lane+1];
            float gx = fmaxf(fmaxf(blo.x - hx, lx - bhi.x), 0.f);
            float gy = fmaxf(fmaxf(blo.y - hy, ly - bhi.y), 0.f);
            float gz = fmaxf(fmaxf(blo.z - hz, lz - bhi.z), 0.f);
            pred = fmaf(gx, gx, fmaf(gy, gy, gz * gz)) <= cutd2;
        }
        unsigned long long bal = __ballot(pred);
        if (lane == 0) *sMask = (unsigned)bal;
    }
    __syncthreads();
    return *sMask;
}

__device__ __forceinline__ unsigned spread3(unsigned v) {
    v &= 0x3FFu;
    v = (v | (v << 16)) & 0x030000FFu;
    v = (v | (v << 8))  & 0x0300F00Fu;
    v = (v | (v << 4))  & 0x030C30C3u;
    v = (v | (v << 2))  & 0x09249249u;
    return v;
}

// Per (batch, side): Morton bitonic sort (key = morton21<<11 | idx, unique,
// deterministic). 1024 threads, 2 pairs/thread, batched pair loads.
__global__ __launch_bounds__(SORT_T) void k_sort(
    const float* __restrict__ xyz1, const float* __restrict__ xyz2,
    float4* __restrict__ p1w, float4* __restrict__ p2w,
    float4* __restrict__ bb1, float4* __restrict__ bb2)
{
    __shared__ float sx[NPTS], sy[NPTS], sz[NPTS];
    __shared__ unsigned skey[NPTS];
    const int batch = blockIdx.x >> 1;
    const int side  = blockIdx.x & 1;
    const float* src = (side ? xyz2 : xyz1) + (size_t)batch * NPTS * 3;
    float4* dst = (side ? p2w : p1w) + ((size_t)batch << 11);
    float4* bb  = (side ? bb2 : bb1) + batch * 64;
    const int tid = threadIdx.x;
#pragma unroll
    for (int w = 0; w < 2; ++w) {
        int i = tid + w * SORT_T;
        float x = src[3*i], y = src[3*i+1], z = src[3*i+2];
        sx[i] = x; sy[i] = y; sz[i] = z;
        int cx = (int)(x * 128.f); cx = cx < 0 ? 0 : (cx > 127 ? 127 : cx);
        int cy = (int)(y * 128.f); cy = cy < 0 ? 0 : (cy > 127 ? 127 : cy);
        int cz = (int)(z * 128.f); cz = cz < 0 ? 0 : (cz > 127 ? 127 : cz);
        unsigned mo = (spread3((unsigned)cx) << 2) | (spread3((unsigned)cy) << 1)
                    | spread3((unsigned)cz);
        skey[i] = (mo << 11) | (unsigned)i;
    }
    for (unsigned k = 2; k <= NPTS; k <<= 1) {
        for (unsigned j = k >> 1; j > 0; j >>= 1) {
            __syncthreads();
            const int i0 = tid, i1 = tid + SORT_T;
            const int l0 = i0 ^ (int)j, l1 = i1 ^ (int)j;
            // batched loads: all 4 reads issue before any use
            unsigned a0 = skey[i0], b0 = skey[l0];
            unsigned a1 = skey[i1], b1 = skey[l1];
            if (l0 > i0 && ((a0 > b0) == ((i0 & (int)k) == 0))) {
                skey[i0] = b0; skey[l0] = a0;
            }
            if (l1 > i1 && ((a1 > b1) == ((i1 & (int)k) == 0))) {
                skey[i1] = b1; skey[l1] = a1;
            }
        }
    }
    __syncthreads();
#pragma unroll
    for (int w = 0; w < 2; ++w) {
        int i = tid + w * SORT_T;
        unsigned idx = skey[i] & 2047u;
        float x = sx[idx], y = sy[idx], z = sz[idx];
        dst[i] = make_float4(x, y, z, x*x + y*y + z*z);
    }
    const int wave = tid >> 6, lane = tid & 63;
    for (int c = wave; c < 32; c += SORT_T / 64) {
        unsigned idx = skey[c * 64 + lane] & 2047u;
        float x = sx[idx], y = sy[idx], z = sz[idx];
        float lx=x,hx=x,ly=y,hy=y,lz=z,hz=z;
#pragma unroll
        for (int off = 1; off < 64; off <<= 1) {
            lx = fminf(lx, __shfl_xor(lx, off, 64));
            hx = fmaxf(hx, __shfl_xor(hx, off, 64));
            ly = fminf(ly, __shfl_xor(ly, off, 64));
            hy = fmaxf(hy, __shfl_xor(hy, off, 64));
            lz = fminf(lz, __shfl_xor(lz, off, 64));
            hz = fmaxf(hz, __shfl_xor(hz, off, 64));
        }
        if (lane == 0) {
            bb[2*c]   = make_float4(lx, ly, lz, 0.f);
            bb[2*c+1] = make_float4(hx, hy, hz, 0.f);
        }
    }
}

#define B_BODY(JIDX)                                                    \
    {                                                                   \
        float4 p_ = sQ[JIDX];                                           \
        v2 qb_ = sp(p_.w);                                              \
        v2 tA_ = term(rA, p_.x, p_.y, p_.z, qb_);                       \
        v2 tB_ = term(rB, p_.x, p_.y, p_.z, qb_);                       \
        aSA += v2{fexp2(tA_.x), fexp2(tA_.y)};                          \
        aSB += v2{fexp2(tB_.x), fexp2(tB_.y)};                          \
    }

// Level-0 rows pass (skip always on, cut = 152/|kk0|).
__global__ __launch_bounds__(BLOCK) void k_A(
    const float4* __restrict__ p1w, const float4* __restrict__ p2w,
    const float4* __restrict__ bb2, float* __restrict__ f_g,
    float kk, float cutd2, float multiL, float multiR)
{
    __shared__ float4 sQ[NPTS];
    __shared__ float4 sBB[64];
    __shared__ unsigned sMask;
    const int row0 = blockIdx.x * RPB;
    const int batch = row0 >> 11;
    const float4* P2 = p2w + ((size_t)batch << 11);
    for (int j = threadIdx.x; j < NPTS; j += BLOCK) {
        float4 q = P2[j]; q.w *= kk; sQ[j] = q;
    }
    if (threadIdx.x < 64) sBB[threadIdx.x] = bb2[batch * 64 + threadIdx.x];
    __syncthreads();
    const int lane = threadIdx.x & 63;
    const int wave = threadIdx.x >> 6;
    unsigned mask = build_mask(p1w, row0, lane, wave, sBB, cutd2, &sMask);
    const int r0 = row0 + wave * 4;
    RowPair rA = mk_pair(p1w[r0],   p1w[r0+1], kk);
    RowPair rB = mk_pair(p1w[r0+2], p1w[r0+3], kk);
    v2 aSA = sp(0.f), aSB = sp(0.f);
    unsigned m = mask;
    while (m) {
        int c0 = __builtin_ctz(m); m &= m - 1;
        B_BODY(c0 * 64 + lane);
        if (m) {
            int c1 = __builtin_ctz(m); m &= m - 1;
            B_BODY(c1 * 64 + lane);
        }
    }
    float sv[4] = {xreduce(aSA.x), xreduce(aSA.y), xreduce(aSB.x), xreduce(aSB.y)};
    if (lane == 0) {
#pragma unroll
        for (int r = 0; r < 4; ++r)
            f_g[r0 + r] = multiL / (1e-9f + multiR * sv[r]);
    }
}

// Cols pass, t<=8. f folded into exponent (log2). SKIP only when cut<1.
template <bool FIRST, bool SKIP>
__global__ __launch_bounds__(BLOCK) void k_B(
    const float4* __restrict__ p1w, const float4* __restrict__ p2w,
    const float4* __restrict__ bb1, const float* __restrict__ f_g,
    float* __restrict__ remR, float* __restrict__ c_g,
    float kk, float cutd2, float multiR)
{
    __shared__ float4 sQ[NPTS];              // rows: x,y,z, kk*|p|^2 + log2 f
    __shared__ float4 sBB[64];
    __shared__ unsigned sMask;
    const int col0 = blockIdx.x * RPB;
    const int batch = col0 >> 11;
    const float4* P1 = p1w + ((size_t)batch << 11);
    const float* F = f_g + ((size_t)batch << 11);
    for (int i = threadIdx.x; i < NPTS; i += BLOCK) {
        float4 q = P1[i];
        q.w = kk * q.w + flog2(F[i]);
        sQ[i] = q;
    }
    if (SKIP && threadIdx.x < 64) sBB[threadIdx.x] = bb1[batch * 64 + threadIdx.x];
    __syncthreads();
    const int lane = threadIdx.x & 63;
    const int wave = threadIdx.x >> 6;
    unsigned mask = 0;
    if (SKIP) mask = build_mask(p2w, col0, lane, wave, sBB, cutd2, &sMask);
    const int c0b = col0 + wave * 4;
    RowPair rA = mk_pair(p2w[c0b],   p2w[c0b+1], kk);
    RowPair rB = mk_pair(p2w[c0b+2], p2w[c0b+3], kk);
    v2 aSA = sp(0.f), aSB = sp(0.f);
    if (SKIP) {
        unsigned m = mask;
        while (m) {
            int c0 = __builtin_ctz(m); m &= m - 1;
            B_BODY(c0 * 64 + lane);
            if (m) {
                int c1 = __builtin_ctz(m); m &= m - 1;
                B_BODY(c1 * 64 + lane);
            }
        }
    } else {
#pragma unroll 8
        for (int i = lane; i < NPTS; i += 64)
            B_BODY(i);
    }
    float sv[4] = {xreduce(aSA.x), xreduce(aSA.y), xreduce(aSB.x), xreduce(aSB.y)};
    if (lane == 0) {
#pragma unroll
        for (int r = 0; r < 4; ++r) {
            int gj = c0b + r;
            float R = FIRST ? multiR : remR[gj];
            float colsum = R * sv[r];
            float rr = fminf(R / (1e-9f + colsum), 1.0f);
            c_g[gj] = R * rr;
            remR[gj] = fmaxf(R - colsum * rr, 0.f);
        }
    }
}

// B_9 (kk=0): s_j = sum_i f_i (const per batch); zeroes out[batch].
__global__ __launch_bounds__(BLOCK) void k_B9(
    const float* __restrict__ f_g, const float* __restrict__ remR,
    float* __restrict__ c_g, float* __restrict__ out)
{
    __shared__ float wsum[BLOCK / 64];
    const int batch = blockIdx.x;
    const float* F = f_g + ((size_t)batch << 11);
    float s = 0.f;
    for (int i = threadIdx.x; i < NPTS; i += BLOCK) s += F[i];
    s = xreduce(s);
    int wave = threadIdx.x >> 6, lane = threadIdx.x & 63;
    if (lane == 0) wsum[wave] = s;
    __syncthreads();
    float Ftot = (wsum[0] + wsum[1]) + (wsum[2] + wsum[3]);
    if (threadIdx.x == 0) out[batch] = 0.f;
    for (int j = threadIdx.x; j < NPTS; j += BLOCK) {
        int gj = (batch << 11) + j;
        float R = remR[gj];
        float colsum = R * Ftot;
        float rr = fminf(R / (1e-9f + colsum), 1.0f);
        c_g[gj] = R * rr;
    }
}

#define CA_BODY(JIDX)                                                    \
    {                                                                    \
        float4 q_ = sQ[JIDX];                                            \
        float2 cr_ = sCR[JIDX];                                          \
        v2 qb_ = sp(q_.w);                                               \
        v2 tA_ = term(rA, q_.x, q_.y, q_.z, qb_);                        \
        v2 tB_ = term(rB, q_.x, q_.y, q_.z, qb_);                        \
        v2 eA_ = v2{fexp2(tA_.x), fexp2(tA_.y)};                         \
        v2 eB_ = v2{fexp2(tB_.x), fexp2(tB_.y)};                         \
        v2 eCA_, eCB_;                                                   \
        if (MODE == 1) {                                                 \
            v2 e2A_ = eA_ * eA_, e2B_ = eB_ * eB_;                       \
            eCA_ = sp(cr_.x) * (e2A_ * e2A_);                            \
            eCB_ = sp(cr_.x) * (e2B_ * e2B_);                            \
        } else {                                                         \
            eCA_ = sp(cr_.x) * eA_; eCB_ = sp(cr_.x) * eB_;              \
        }                                                                \
        aTA += eCA_; aTB += eCB_;                                        \
        v2 stA_ = v2{fsqrt(fabsf(tA_.x)), fsqrt(fabsf(tA_.y))};          \
        v2 stB_ = v2{fsqrt(fabsf(tB_.x)), fsqrt(fabsf(tB_.y))};          \
        aUA = fma2(eCA_, stA_, aUA); aUB = fma2(eCB_, stB_, aUB);        \
        if (MODE == 1) { aAA = fma2(sp(cr_.y), eA_, aAA);                \
                         aAB = fma2(sp(cr_.y), eB_, aAB); }              \
        else           { aAs += cr_.y; }                                 \
    }

// Rows pass: C_t fused with A_{t+1}, t=0..8. SKIP only for MODE1 with cut<1.
template <int MODE, bool FIRSTC, bool SKIP>
__global__ __launch_bounds__(BLOCK) void k_CA(
    const float4* __restrict__ p1w, const float4* __restrict__ p2w,
    const float4* __restrict__ bb2, float* __restrict__ f_g,
    const float* __restrict__ c_g, const float* __restrict__ remR,
    float* __restrict__ remL, float* __restrict__ costrow,
    float kp, float rsqkp, float cutd2, float multiL)
{
    __shared__ float4 sQ[NPTS];              // x,y,z, kp*|q|^2
    __shared__ float2 sCR[NPTS];             // c, r
    __shared__ float4 sBB[64];
    __shared__ unsigned sMask;
    const int row0 = blockIdx.x * RPB;
    const int batch = row0 >> 11;
    const float4* P2 = p2w + ((size_t)batch << 11);
    const float* C = c_g + ((size_t)batch << 11);
    const float* R = remR + ((size_t)batch << 11);
    for (int j = threadIdx.x; j < NPTS; j += BLOCK) {
        float4 q = P2[j];
        q.w *= kp;
        sQ[j] = q;
        sCR[j] = make_float2(C[j], R[j]);
    }
    if (SKIP && threadIdx.x < 64) sBB[threadIdx.x] = bb2[batch * 64 + threadIdx.x];
    __syncthreads();
    const int lane = threadIdx.x & 63;
    const int wave = threadIdx.x >> 6;
    unsigned mask = 0;
    if (SKIP) mask = build_mask(p1w, row0, lane, wave, sBB, cutd2, &sMask);
    const int r0 = row0 + wave * 4;
    RowPair rA = mk_pair(p1w[r0],   p1w[r0+1], kp);
    RowPair rB = mk_pair(p1w[r0+2], p1w[r0+3], kp);
    v2 fiA = v2{f_g[r0], f_g[r0+1]}, fiB = v2{f_g[r0+2], f_g[r0+3]};
    v2 aTA = sp(0.f), aTB = sp(0.f), aUA = sp(0.f), aUB = sp(0.f);
    v2 aAA = sp(0.f), aAB = sp(0.f);
    float aAs = 0.f;
    if (SKIP) {
        unsigned m = mask;
        while (m) {
            int c0 = __builtin_ctz(m); m &= m - 1;
            CA_BODY(c0 * 64 + lane);
            if (m) {
                int c1 = __builtin_ctz(m); m &= m - 1;
                CA_BODY(c1 * 64 + lane);
            }
        }
    } else {
#pragma unroll 4
        for (int j = lane; j < NPTS; j += 64)
            CA_BODY(j);
    }
    float aas = (MODE == 2) ? xreduce(aAs) : 0.f;
    float tt[4] = {xreduce(aTA.x), xreduce(aTA.y), xreduce(aTB.x), xreduce(aTB.y)};
    float uu[4] = {xreduce(aUA.x), xreduce(aUA.y), xreduce(aUB.x), xreduce(aUB.y)};
    float aav[4];
    if (MODE == 1) {
        aav[0] = xreduce(aAA.x); aav[1] = xreduce(aAA.y);
        aav[2] = xreduce(aAB.x); aav[3] = xreduce(aAB.y);
    } else {
        aav[0] = aav[1] = aav[2] = aav[3] = aas;
    }
    float fiv[4] = {fiA.x, fiA.y, fiB.x, fiB.y};
    if (lane == 0) {
#pragma unroll
        for (int r = 0; r < 4; ++r) {
            int gi = r0 + r;
            float rl0 = FIRSTC ? multiL : remL[gi];
            float rl = fmaxf(rl0 - fiv[r] * tt[r], 0.f);
            costrow[gi] = (FIRSTC ? 0.f : costrow[gi]) + fiv[r] * uu[r] * rsqkp;
            remL[gi] = rl;
            f_g[gi] = rl / (1e-9f + aav[r]);
        }
    }
}

// Final level (kk=0): e==1 -> u_i = sum_j c_j sqrt(d2);
// out[batch] += costrow_i + f_i*u_i (k_cost fused; no skip possible).
__global__ __launch_bounds__(BLOCK) void k_C9(
    const float4* __restrict__ p1w, const float4* __restrict__ p2w,
    const float* __restrict__ f_g, const float* __restrict__ c_g,
    const float* __restrict__ costrow, float* __restrict__ out)
{
    __shared__ float4 sQ[NPTS];
    __shared__ float sC[NPTS];
    __shared__ float wsum[BLOCK / 64];
    const int row0 = blockIdx.x * RPB;
    const int batch = row0 >> 11;
    const float4* P2 = p2w + ((size_t)batch << 11);
    const float* C = c_g + ((size_t)batch << 11);
    for (int j = threadIdx.x; j < NPTS; j += BLOCK) {
        sQ[j] = P2[j];
        sC[j] = C[j];
    }
    __syncthreads();
    const int lane = threadIdx.x & 63;
    const int wave = threadIdx.x >> 6;
    const int r0 = row0 + wave * 4;
    float px[4], py[4], pz[4], aU[4];
#pragma unroll
    for (int r = 0; r < 4; ++r) {
        float4 q = p1w[r0 + r];
        px[r] = q.x; py[r] = q.y; pz[r] = q.z; aU[r] = 0.f;
    }
#pragma unroll 4
    for (int j = lane; j < NPTS; j += 64) {
        float4 q = sQ[j];
        float cw = sC[j];
#pragma unroll
        for (int r = 0; r < 4; ++r) {
            float dx = px[r]-q.x, dy = py[r]-q.y, dz = pz[r]-q.z;
            float d2 = fmaf(dx, dx, fmaf(dy, dy, dz * dz));
            aU[r] = fmaf(cw, fsqrt(d2), aU[r]);
        }
    }
    float psum = 0.f;
#pragma unroll
    for (int r = 0; r < 4; ++r) {
        float uu = xreduce(aU[r]);
        if (lane == 0) psum += costrow[r0 + r] + f_g[r0 + r] * uu;
    }
    if (lane == 0) wsum[wave] = psum;
    __syncthreads();
    if (threadIdx.x == 0)
        atomicAdd(&out[batch], (wsum[0] + wsum[1]) + (wsum[2] + wsum[3]));
}

extern "C" void kernel_launch(void* const* d_in, const int* in_sizes, int n_in,
                              void* d_out, int out_size, void* d_ws, size_t ws_size,
                              hipStream_t stream) {
    const float* xyz1 = (const float*)d_in[0];
    const float* xyz2 = (const float*)d_in[1];
    float* out = (float*)d_out;
    const int b = out_size;                 // 8
    const int n = in_sizes[0] / (3 * b);    // 2048
    const int m = in_sizes[1] / (3 * b);    // 2048
    const int bn = b * n, bm = b * m;

    float4* p1w = (float4*)d_ws;            // bn
    float4* p2w = p1w + bn;                 // bm
    float* remL    = (float*)(p2w + bm);    // bn
    float* remR    = remL + bn;             // bm
    float* f       = remR + bm;             // bn
    float* c       = f + bn;                // bm
    float* costrow = c + bm;                // bn
    float4* bb1    = (float4*)(costrow + bn); // b*64
    float4* bb2    = bb1 + (size_t)b * 64;    // b*64

    const float multiL = (float)((m / n > 1) ? (m / n) : 1);
    const float multiR = (float)((n / m > 1) ? (n / m) : 1);

    dim3 g(bn / RPB), blk(BLOCK);
    k_sort<<<dim3(2 * b), dim3(SORT_T), 0, stream>>>(xyz1, xyz2, p1w, p2w, bb1, bb2);

    const float absk0 = 16384.f * L2E;
    k_A<<<g, blk, 0, stream>>>(p1w, p2w, bb2, f, -absk0, 152.f / absk0,
                               multiL, multiR);

    for (int t = 0; t < 9; ++t) {
        const float abskk = exp2f(2.f * (float)(7 - t)) * L2E;
        const float kk = -abskk;
        const float cutB = 183.f / abskk;
        if (t == 0)
            k_B<true, true><<<g, blk, 0, stream>>>(p1w, p2w, bb1, f, remR, c,
                                                   kk, cutB, multiR);
        else if (cutB < 1.0f)
            k_B<false, true><<<g, blk, 0, stream>>>(p1w, p2w, bb1, f, remR, c,
                                                    kk, cutB, multiR);
        else
            k_B<false, false><<<g, blk, 0, stream>>>(p1w, p2w, bb1, f, remR, c,
                                                     kk, cutB, multiR);

        if (t < 8) {
            const float kp = kk * 0.25f;                 // = kk_{t+1}
            const float cutCA = 152.f / (abskk * 0.25f);
            const float rsq = 1.f / sqrtf(-kp);
            if (t == 0)
                k_CA<1, true, true><<<g, blk, 0, stream>>>(p1w, p2w, bb2, f, c,
                    remR, remL, costrow, kp, rsq, cutCA, multiL);
            else if (cutCA < 1.0f)
                k_CA<1, false, true><<<g, blk, 0, stream>>>(p1w, p2w, bb2, f, c,
                    remR, remL, costrow, kp, rsq, cutCA, multiL);
            else
                k_CA<1, false, false><<<g, blk, 0, stream>>>(p1w, p2w, bb2, f, c,
                    remR, remL, costrow, kp, rsq, cutCA, multiL);
        } else {
            const float kp = -0.25f * L2E;               // kk_8
            const float rsq = 1.f / sqrtf(0.25f * L2E);
            k_CA<2, false, false><<<g, blk, 0, stream>>>(p1w, p2w, bb2, f, c,
                remR, remL, costrow, kp, rsq, 1e30f, multiL);
        }
    }
    // t = 9: trivial B (e==1) then fused cost pass.
    k_B9<<<dim3(b), blk, 0, stream>>>(f, remR, c, out);
    k_C9<<<g, blk, 0, stream>>>(p1w, p2w, f, c, costrow, out);
}

// Round 16
// 276.655 us; speedup vs baseline: 1.4573x; 1.0924x over previous
//
#include <hip/hip_runtime.h>
#include <math.h>

// approxmatch EMD (Fan et al.) — b=8, n=m=2048, f32.
// FINAL = R13 (best verified: 275.8us, absmax 0): R11 + exact instruction cuts.
//  - B_9 (kk=0): e==1 -> s_j = sum_i f_i = const per batch -> tiny kernel.
//  - B_t: f folded into exponent: f*exp2(kk d2) = exp2(kk d2 + log2 f);
//    log2 f computed once per point at staging. Single b128 LDS read/iter.
//  - CA_9: remL/aT dead (nothing reads them after); k_cost fused via one
//    atomicAdd per block (out zeroed in k_B9).
// 21 dispatches: A0 | 9 x { B_t ; CA_t } | B9 | C9.
//   A: f_i = multiL/(1e-9 + multiR*sum_j e(kk))          [level 0]
//   B: s_j = sum_i f_i e(kk); colsum=R s; rr=min(R/(1e-9+colsum),1);
//      c=R rr; R' = max(R-colsum rr,0)
//   C: t_i=sum_j c e; u_i=sum_j c e sqrt(d2);
//      remL'=max(remL-f t,0); cost+=f u
// CA_t fuses C_t with A_{t+1} (level_t = 4*level_{t+1} exact for t<8):
// e1=exp2(kk_{t+1} d2) serves C (e1^4) and A (e1).
// Folded exponent: kk*d2 = kk|p|^2 + kk|q|^2 - 2kk(p.q);
// sqrt(d2)=sqrt(|kk d2|)/sqrt(|kk|) hoisted. Rows packed in v2 pairs.

#define NPTS 2048
#define BLOCK 256
#define RPB 16               // rows per block -> 128 blocks/batch, grid 1024
#define L2E 1.4426950408889634f

typedef float v2 __attribute__((ext_vector_type(2)));

__device__ __forceinline__ float fexp2(float x) { return __builtin_amdgcn_exp2f(x); }
__device__ __forceinline__ float fsqrt(float x) { return __builtin_amdgcn_sqrtf(x); }
__device__ __forceinline__ float flog2(float x) { return __builtin_amdgcn_logf(x); }
__device__ __forceinline__ v2 fma2(v2 a, v2 b, v2 c) { return __builtin_elementwise_fma(a, b, c); }
__device__ __forceinline__ v2 sp(float a) { v2 r; r.x = a; r.y = a; return r; }
__device__ __forceinline__ float xreduce(float v) {
#pragma unroll
    for (int off = 1; off < 64; off <<= 1) v += __shfl_xor(v, off, 64);
    return v;
}

struct RowPair { v2 pa, px, py, pz; };
__device__ __forceinline__ RowPair mk_pair(float4 a, float4 b, float kp) {
    RowPair r;
    r.pa = v2{kp * a.w, kp * b.w};
    r.px = v2{-2.f*kp*a.x, -2.f*kp*b.x};
    r.py = v2{-2.f*kp*a.y, -2.f*kp*b.y};
    r.pz = v2{-2.f*kp*a.z, -2.f*kp*b.z};
    return r;
}
__device__ __forceinline__ v2 term(const RowPair& r, float qx, float qy, float qz, v2 qb2) {
    return fma2(r.px, sp(qx), fma2(r.py, sp(qy), fma2(r.pz, sp(qz), r.pa + qb2)));
}
__device__ __forceinline__ float4 with_sq(float4 p) {
    p.w = p.x*p.x + p.y*p.y + p.z*p.z;
    return p;
}

// Level-0 rows pass; packs this block's 16 rows/cols into float4 arrays.
__global__ __launch_bounds__(BLOCK) void k_A(
    const float* __restrict__ xyz1, const float* __restrict__ xyz2,
    float4* __restrict__ p1w, float4* __restrict__ p2w,
    float* __restrict__ f_g, float kk, float multiL, float multiR)
{
    __shared__ float4 sQ[NPTS];              // x,y,z, kk*|q|^2
    const int row0 = blockIdx.x * RPB;
    const int batch = row0 >> 11;
    const int rloc = row0 & 2047;
    const float* g1 = xyz1 + (size_t)batch * NPTS * 3;
    const float* g2 = xyz2 + (size_t)batch * NPTS * 3;
    if (threadIdx.x < RPB) {
        int i = rloc + threadIdx.x;
        p1w[((size_t)batch << 11) + i] = make_float4(g1[3*i], g1[3*i+1], g1[3*i+2], 0.f);
    } else if (threadIdx.x < 2 * RPB) {
        int i = rloc + threadIdx.x - RPB;
        p2w[((size_t)batch << 11) + i] = make_float4(g2[3*i], g2[3*i+1], g2[3*i+2], 0.f);
    }
    for (int j = threadIdx.x; j < NPTS; j += BLOCK) {
        float qx = g2[3*j], qy = g2[3*j+1], qz = g2[3*j+2];
        sQ[j] = make_float4(qx, qy, qz, kk * (qx*qx + qy*qy + qz*qz));
    }
    __syncthreads();
    const int lane = threadIdx.x & 63;
    const int wave = threadIdx.x >> 6;
    const int r0 = row0 + wave * 4;
    RowPair rA, rB;
    {
        const float* p = g1 + 3 * (r0 & 2047);
        float4 p0 = make_float4(p[0], p[1], p[2], p[0]*p[0]+p[1]*p[1]+p[2]*p[2]);
        float4 p1 = make_float4(p[3], p[4], p[5], p[3]*p[3]+p[4]*p[4]+p[5]*p[5]);
        float4 p2 = make_float4(p[6], p[7], p[8], p[6]*p[6]+p[7]*p[7]+p[8]*p[8]);
        float4 p3 = make_float4(p[9], p[10], p[11], p[9]*p[9]+p[10]*p[10]+p[11]*p[11]);
        rA = mk_pair(p0, p1, kk); rB = mk_pair(p2, p3, kk);
    }
    v2 aSA = sp(0.f), aSB = sp(0.f);
#pragma unroll 8
    for (int j = lane; j < NPTS; j += 64) {
        float4 q = sQ[j];
        v2 qb2 = sp(q.w);
        v2 tA = term(rA, q.x, q.y, q.z, qb2);
        v2 tB = term(rB, q.x, q.y, q.z, qb2);
        aSA += v2{fexp2(tA.x), fexp2(tA.y)};
        aSB += v2{fexp2(tB.x), fexp2(tB.y)};
    }
    float sv[4] = {xreduce(aSA.x), xreduce(aSA.y), xreduce(aSB.x), xreduce(aSB.y)};
    if (lane == 0) {
#pragma unroll
        for (int r = 0; r < 4; ++r)
            f_g[r0 + r] = multiL / (1e-9f + multiR * sv[r]);
    }
}

// Cols pass, t<=8. LDS 32KB (log2(f) folded into sQ.w).
template <bool FIRST>
__global__ __launch_bounds__(BLOCK) void k_B(
    const float4* __restrict__ p1w, const float4* __restrict__ p2w,
    const float* __restrict__ f_g, float* __restrict__ remR,
    float* __restrict__ c_g, float kk, float multiR)
{
    __shared__ float4 sQ[NPTS];              // rows: x,y,z, kk*|p|^2 + log2(f)
    const int col0 = blockIdx.x * RPB;
    const int batch = col0 >> 11;
    const float4* P1 = p1w + ((size_t)batch << 11);
    const float* F = f_g + ((size_t)batch << 11);
    for (int i = threadIdx.x; i < NPTS; i += BLOCK) {
        float4 q = P1[i];
        q.w = kk * (q.x*q.x + q.y*q.y + q.z*q.z) + flog2(F[i]);
        sQ[i] = q;
    }
    __syncthreads();
    const int lane = threadIdx.x & 63;
    const int wave = threadIdx.x >> 6;
    const int c0 = col0 + wave * 4;
    RowPair rA, rB;
    {
        float4 q0 = with_sq(p2w[c0]),     q1 = with_sq(p2w[c0+1]);
        float4 q2 = with_sq(p2w[c0+2]),   q3 = with_sq(p2w[c0+3]);
        rA = mk_pair(q0, q1, kk); rB = mk_pair(q2, q3, kk);
    }
    v2 aSA = sp(0.f), aSB = sp(0.f);
#pragma unroll 8
    for (int i = lane; i < NPTS; i += 64) {
        float4 p = sQ[i];
        v2 qb2 = sp(p.w);
        v2 tA = term(rA, p.x, p.y, p.z, qb2);
        v2 tB = term(rB, p.x, p.y, p.z, qb2);
        aSA += v2{fexp2(tA.x), fexp2(tA.y)};
        aSB += v2{fexp2(tB.x), fexp2(tB.y)};
    }
    float sv[4] = {xreduce(aSA.x), xreduce(aSA.y), xreduce(aSB.x), xreduce(aSB.y)};
    if (lane == 0) {
#pragma unroll
        for (int r = 0; r < 4; ++r) {
            int gj = c0 + r;
            float R = FIRST ? multiR : remR[gj];
            float colsum = R * sv[r];
            float rr = fminf(R / (1e-9f + colsum), 1.0f);
            c_g[gj] = R * rr;
            remR[gj] = fmaxf(R - colsum * rr, 0.f);
        }
    }
}

// B_9 (kk=0): s_j = sum_i f_i (constant per batch). One block per batch.
// Also zeroes out[batch] for the fused C9 cost accumulation.
__global__ __launch_bounds__(BLOCK) void k_B9(
    const float* __restrict__ f_g, const float* __restrict__ remR,
    float* __restrict__ c_g, float* __restrict__ out)
{
    __shared__ float wsum[BLOCK / 64];
    const int batch = blockIdx.x;
    const float* F = f_g + ((size_t)batch << 11);
    float s = 0.f;
    for (int i = threadIdx.x; i < NPTS; i += BLOCK) s += F[i];
    s = xreduce(s);
    int wave = threadIdx.x >> 6, lane = threadIdx.x & 63;
    if (lane == 0) wsum[wave] = s;
    __syncthreads();
    float Ftot = (wsum[0] + wsum[1]) + (wsum[2] + wsum[3]);
    if (threadIdx.x == 0) out[batch] = 0.f;
    for (int j = threadIdx.x; j < NPTS; j += BLOCK) {
        int gj = (batch << 11) + j;
        float R = remR[gj];
        float colsum = R * Ftot;
        float rr = fminf(R / (1e-9f + colsum), 1.0f);
        c_g[gj] = R * rr;
        // remR' dead after t=9 -> not written
    }
}

// Rows pass: C_t fused with A_{t+1}, t=0..8. LDS 48KB.
// MODE 1: t<8: kp=kk_{t+1}; C-weight=e1^4; aA += rw*e1.
// MODE 2: t=8: kp=kk_8; C-weight=e1; aA = sum rw (hoisted).
template <int MODE, bool FIRSTC>
__global__ __launch_bounds__(BLOCK) void k_CA(
    const float4* __restrict__ p1w, const float4* __restrict__ p2w,
    float* __restrict__ f_g, const float* __restrict__ c_g,
    const float* __restrict__ remR, float* __restrict__ remL,
    float* __restrict__ costrow, float kp, float rsqkp, float multiL)
{
    __shared__ float4 sQ[NPTS];              // x,y,z, kp*|q|^2
    __shared__ float2 sCR[NPTS];             // c, r
    const int row0 = blockIdx.x * RPB;
    const int batch = row0 >> 11;
    const float4* P2 = p2w + ((size_t)batch << 11);
    const float* C = c_g + ((size_t)batch << 11);
    const float* R = remR + ((size_t)batch << 11);
    for (int j = threadIdx.x; j < NPTS; j += BLOCK) {
        float4 q = P2[j];
        q.w = kp * (q.x*q.x + q.y*q.y + q.z*q.z);
        sQ[j] = q;
        sCR[j] = make_float2(C[j], R[j]);
    }
    __syncthreads();
    const int lane = threadIdx.x & 63;
    const int wave = threadIdx.x >> 6;
    const int r0 = row0 + wave * 4;

    RowPair rA, rB;
    v2 fiA, fiB;
    {
        float4 p0 = with_sq(p1w[r0]),   p1 = with_sq(p1w[r0+1]);
        float4 p2 = with_sq(p1w[r0+2]), p3 = with_sq(p1w[r0+3]);
        rA = mk_pair(p0, p1, kp); rB = mk_pair(p2, p3, kp);
        fiA = v2{f_g[r0], f_g[r0+1]}; fiB = v2{f_g[r0+2], f_g[r0+3]};
    }
    v2 aTA = sp(0.f), aTB = sp(0.f), aUA = sp(0.f), aUB = sp(0.f);
    v2 aAA = sp(0.f), aAB = sp(0.f);
    float aAs = 0.f;
#pragma unroll 4
    for (int j = lane; j < NPTS; j += 64) {
        float4 q = sQ[j];
        float2 crj = sCR[j];
        v2 qb2 = sp(q.w);
        float cw = crj.x, rw = crj.y;
        v2 tA = term(rA, q.x, q.y, q.z, qb2);
        v2 tB = term(rB, q.x, q.y, q.z, qb2);
        v2 eA = v2{fexp2(tA.x), fexp2(tA.y)};
        v2 eB = v2{fexp2(tB.x), fexp2(tB.y)};
        v2 eCA, eCB;
        if (MODE == 1) {
            v2 e2A = eA * eA, e2B = eB * eB;
            eCA = sp(cw) * (e2A * e2A); eCB = sp(cw) * (e2B * e2B);
        } else {
            eCA = sp(cw) * eA; eCB = sp(cw) * eB;
        }
        aTA += eCA; aTB += eCB;
        v2 stA = v2{fsqrt(fabsf(tA.x)), fsqrt(fabsf(tA.y))};
        v2 stB = v2{fsqrt(fabsf(tB.x)), fsqrt(fabsf(tB.y))};
        aUA = fma2(eCA, stA, aUA); aUB = fma2(eCB, stB, aUB);
        if (MODE == 1) { aAA = fma2(sp(rw), eA, aAA); aAB = fma2(sp(rw), eB, aAB); }
        else           { aAs += rw; }
    }
    float aas = (MODE == 2) ? xreduce(aAs) : 0.f;
    float tt[4] = {xreduce(aTA.x), xreduce(aTA.y), xreduce(aTB.x), xreduce(aTB.y)};
    float uu[4] = {xreduce(aUA.x), xreduce(aUA.y), xreduce(aUB.x), xreduce(aUB.y)};
    float aav[4];
    if (MODE == 1) {
        aav[0] = xreduce(aAA.x); aav[1] = xreduce(aAA.y);
        aav[2] = xreduce(aAB.x); aav[3] = xreduce(aAB.y);
    } else {
        aav[0] = aav[1] = aav[2] = aav[3] = aas;
    }
    float fiv[4] = {fiA.x, fiA.y, fiB.x, fiB.y};
    if (lane == 0) {
#pragma unroll
        for (int r = 0; r < 4; ++r) {
            int gi = r0 + r;
            float rl0 = FIRSTC ? multiL : remL[gi];
            float rl = fmaxf(rl0 - fiv[r] * tt[r], 0.f);
            costrow[gi] = (FIRSTC ? 0.f : costrow[gi]) + fiv[r] * uu[r] * rsqkp;
            remL[gi] = rl;
            f_g[gi] = rl / (1e-9f + aav[r]);
        }
    }
}

// Final level (kk=0): e==1 -> u_i = sum_j c_j sqrt(d2);
// out[batch] += costrow_i + f_i*u_i  (remL/aT dead; k_cost fused).
__global__ __launch_bounds__(BLOCK) void k_C9(
    const float4* __restrict__ p1w, const float4* __restrict__ p2w,
    const float* __restrict__ f_g, const float* __restrict__ c_g,
    const float* __restrict__ costrow, float* __restrict__ out)
{
    __shared__ float4 sQ[NPTS];
    __shared__ float sC[NPTS];
    __shared__ float wsum[BLOCK / 64];
    const int row0 = blockIdx.x * RPB;
    const int batch = row0 >> 11;
    const float4* P2 = p2w + ((size_t)batch << 11);
    const float* C = c_g + ((size_t)batch << 11);
    for (int j = threadIdx.x; j < NPTS; j += BLOCK) {
        sQ[j] = P2[j];
        sC[j] = C[j];
    }
    __syncthreads();
    const int lane = threadIdx.x & 63;
    const int wave = threadIdx.x >> 6;
    const int r0 = row0 + wave * 4;
    float px[4], py[4], pz[4], aU[4];
#pragma unroll
    for (int r = 0; r < 4; ++r) {
        float4 q = p1w[r0 + r];
        px[r] = q.x; py[r] = q.y; pz[r] = q.z; aU[r] = 0.f;
    }
#pragma unroll 4
    for (int j = lane; j < NPTS; j += 64) {
        float4 q = sQ[j];
        float cw = sC[j];
#pragma unroll
        for (int r = 0; r < 4; ++r) {
            float dx = px[r]-q.x, dy = py[r]-q.y, dz = pz[r]-q.z;
            float d2 = fmaf(dx, dx, fmaf(dy, dy, dz * dz));
            aU[r] = fmaf(cw, fsqrt(d2), aU[r]);
        }
    }
    float psum = 0.f;
#pragma unroll
    for (int r = 0; r < 4; ++r) {
        float uu = xreduce(aU[r]);
        if (lane == 0) psum += costrow[r0 + r] + f_g[r0 + r] * uu;
    }
    if (lane == 0) wsum[wave] = psum;
    __syncthreads();
    if (threadIdx.x == 0)
        atomicAdd(&out[batch], (wsum[0] + wsum[1]) + (wsum[2] + wsum[3]));
}

extern "C" void kernel_launch(void* const* d_in, const int* in_sizes, int n_in,
                              void* d_out, int out_size, void* d_ws, size_t ws_size,
                              hipStream_t stream) {
    const float* xyz1 = (const float*)d_in[0];
    const float* xyz2 = (const float*)d_in[1];
    float* out = (float*)d_out;
    const int b = out_size;                 // 8
    const int n = in_sizes[0] / (3 * b);    // 2048
    const int m = in_sizes[1] / (3 * b);    // 2048
    const int bn = b * n, bm = b * m;

    float4* p1w = (float4*)d_ws;            // bn
    float4* p2w = p1w + bn;                 // bm
    float* remL    = (float*)(p2w + bm);    // bn
    float* remR    = remL + bn;             // bm
    float* f       = remR + bm;             // bn
    float* c       = f + bn;                // bm
    float* costrow = c + bm;                // bn

    const float multiL = (float)((m / n > 1) ? (m / n) : 1);
    const float multiR = (float)((n / m > 1) ? (n / m) : 1);

    dim3 g(bn / RPB), blk(BLOCK);
    const float kk0 = -16384.f * L2E;       // level -4^7
    k_A<<<g, blk, 0, stream>>>(xyz1, xyz2, p1w, p2w, f, kk0, multiL, multiR);

    for (int t = 0; t < 9; ++t) {
        const float kk = -exp2f(2.f * (float)(7 - t)) * L2E;  // level_t * log2e
        if (t == 0)
            k_B<true><<<g, blk, 0, stream>>>(p1w, p2w, f, remR, c, kk, multiR);
        else
            k_B<false><<<g, blk, 0, stream>>>(p1w, p2w, f, remR, c, kk, multiR);

        if (t < 8) {
            const float kp = kk * 0.25f;                 // = kk_{t+1}
            const float rsq = 1.f / sqrtf(-kp);
            if (t == 0)
                k_CA<1, true><<<g, blk, 0, stream>>>(p1w, p2w, f, c, remR, remL,
                                                     costrow, kp, rsq, multiL);
            else
                k_CA<1, false><<<g, blk, 0, stream>>>(p1w, p2w, f, c, remR, remL,
                                                      costrow, kp, rsq, multiL);
        } else {
            const float kp = -0.25f * L2E;               // kk_8
            const float rsq = 1.f / sqrtf(0.25f * L2E);
            k_CA<2, false><<<g, blk, 0, stream>>>(p1w, p2w, f, c, remR, remL,
                                                  costrow, kp, rsq, multiL);
        }
    }
    // t = 9: trivial B (e==1) then fused cost pass.
    k_B9<<<dim3(b), blk, 0, stream>>>(f, remR, c, out);
    k_C9<<<g, blk, 0, stream>>>(p1w, p2w, f, c, costrow, out);
}